// Round 1
// baseline (262.745 us; speedup 1.0000x reference)
//
#include <hip/hip_runtime.h>

#define NTOL 1e-7f

typedef __attribute__((ext_vector_type(8))) short short8;
typedef __attribute__((ext_vector_type(4))) float floatx4;

static __device__ __forceinline__ unsigned short f2bf(float f) {
    unsigned u = __float_as_uint(f);
    u += 0x7FFFu + ((u >> 16) & 1u);
    return (unsigned short)(u >> 16);
}

// ---------------- kernel 0: convert weights fp32 -> bf16 into ws ----------------
__global__ __launch_bounds__(256) void convert_w_k(const float* __restrict__ W1,
                                                   const float* __restrict__ W2,
                                                   unsigned short* __restrict__ w1b,
                                                   unsigned short* __restrict__ w2b) {
    int i = blockIdx.x * 256 + threadIdx.x;  // 16384 threads, exact
    w1b[i] = f2bf(W1[i]);
    w2b[i] = f2bf(W2[i]);
}

// ---------------- kernel 1: Newton solve for s, emit xs(bf16) and e^s ----------------
// 4 threads per sample, 16 coords each; quad-level shuffle reduction.
__global__ __launch_bounds__(256) void newton_k(const float* __restrict__ x,
                                                const float* __restrict__ r,
                                                unsigned short* __restrict__ xs,
                                                float* __restrict__ scl) {
    int tid = blockIdx.x * 256 + threadIdx.x;
    int sample = tid >> 2;
    int part = tid & 3;

    const float4* x4 = (const float4*)(x + (size_t)sample * 64 + part * 16);
    const float4* r4 = (const float4*)(r + part * 16);
    float xv[16], rr[16], x2[16], rx2[16];
#pragma unroll
    for (int j = 0; j < 4; ++j) {
        float4 a = x4[j];
        float4 b = r4[j];
        xv[4 * j + 0] = a.x; xv[4 * j + 1] = a.y; xv[4 * j + 2] = a.z; xv[4 * j + 3] = a.w;
        rr[4 * j + 0] = b.x; rr[4 * j + 1] = b.y; rr[4 * j + 2] = b.z; rr[4 * j + 3] = b.w;
    }

    float sum0 = 0.f, sumr = 0.f;
    int nz = 0;
#pragma unroll
    for (int j = 0; j < 16; ++j) {
        x2[j] = xv[j] * xv[j];
        rx2[j] = rr[j] * x2[j];
        sum0 += x2[j];
        sumr += rx2[j];
        nz |= (fabsf(xv[j]) > 1e-12f) ? 1 : 0;
    }
    sum0 += __shfl_xor(sum0, 1); sum0 += __shfl_xor(sum0, 2);
    sumr += __shfl_xor(sumr, 1); sumr += __shfl_xor(sumr, 2);
    nz   |= __shfl_xor(nz, 1);   nz   |= __shfl_xor(nz, 2);

    float s = 0.f;
    if (nz) {
        // analytic init: exact root for uniform r; by Jensen F(s0) >= 0, so Newton
        // on the convex decreasing F converges monotonically (no overshoot).
        s = __logf(sum0) * sum0 / (2.f * sumr);
        for (int it = 0; it < 30; ++it) {
            float m2s = -2.f * s;
            float v = 0.f, dv = 0.f;
#pragma unroll
            for (int j = 0; j < 16; ++j) {
                float e = __expf(m2s * rr[j]);
                v = fmaf(e, x2[j], v);
                dv = fmaf(e, rx2[j], dv);
            }
            v += __shfl_xor(v, 1);   v += __shfl_xor(v, 2);
            dv += __shfl_xor(dv, 1); dv += __shfl_xor(dv, 2);
            float val = v - 1.f;
            if (fabsf(val) < NTOL) break;  // freeze semantics == early exit
            float dval = -2.f * dv;
            if (dval == 0.f) dval = 1.f;
            s -= val / dval;
        }
    }

    // xs = x * exp(-r*s)  (bf16), scale = exp(NU*s), NU=1
    unsigned up[8];
#pragma unroll
    for (int j = 0; j < 8; ++j) {
        float a = xv[2 * j] * __expf(-s * rr[2 * j]);
        float b = xv[2 * j + 1] * __expf(-s * rr[2 * j + 1]);
        up[j] = (unsigned)f2bf(a) | ((unsigned)f2bf(b) << 16);
    }
    uint4* dst = (uint4*)(xs + (size_t)sample * 64 + part * 16);
    dst[0] = make_uint4(up[0], up[1], up[2], up[3]);
    dst[1] = make_uint4(up[4], up[5], up[6], up[7]);
    if (part == 0) scl[sample] = __expf(s);
}

// ---------------- kernel 2: fused MLP via bf16 MFMA ----------------
// block = 256 threads (4 waves), 64 samples/block (16/wave).
// LDS rows padded +8 bf16 -> 2-way bank aliasing only (free on CDNA4).
#define LDA 72
#define LDW1 72
#define LDW2 264
#define LDH 264

__global__ __launch_bounds__(256) void mlp_k(const unsigned short* __restrict__ xs,
                                             const float* __restrict__ scl,
                                             const unsigned short* __restrict__ w1b,
                                             const unsigned short* __restrict__ w2b,
                                             const float* __restrict__ b1,
                                             const float* __restrict__ b2,
                                             float* __restrict__ out) {
    __shared__ unsigned short sA[64 * LDA];     //  9.0 KB
    __shared__ unsigned short sW1[256 * LDW1];  // 36.0 KB
    __shared__ unsigned short sW2[64 * LDW2];   // 33.0 KB
    __shared__ unsigned short sH[64 * LDH];     // 33.0 KB
    __shared__ float sScale[64];

    int tid = threadIdx.x;
    size_t m0 = (size_t)blockIdx.x * 64;

    // stage W1 [256x64] bf16
    const uint4* w1u = (const uint4*)w1b;
#pragma unroll
    for (int c = 0; c < 8; ++c) {
        int i = tid + c * 256;  // 2048 x uint4 (8 bf16 each)
        int row = i >> 3, part = i & 7;
        *(uint4*)&sW1[row * LDW1 + part * 8] = w1u[i];
    }
    // stage W2 [64x256] bf16
    const uint4* w2u = (const uint4*)w2b;
#pragma unroll
    for (int c = 0; c < 8; ++c) {
        int i = tid + c * 256;
        int row = i >> 5, part = i & 31;
        *(uint4*)&sW2[row * LDW2 + part * 8] = w2u[i];
    }
    // stage Xs tile [64x64] bf16
    const uint4* xu = (const uint4*)(xs + m0 * 64);
#pragma unroll
    for (int c = 0; c < 2; ++c) {
        int i = tid + c * 256;  // 512 x uint4
        int row = i >> 3, part = i & 7;
        *(uint4*)&sA[row * LDA + part * 8] = xu[i];
    }
    if (tid < 64) sScale[tid] = scl[m0 + tid];
    __syncthreads();

    int wave = tid >> 6, lane = tid & 63;
    int quad = lane >> 4, l16 = lane & 15;

    // ---- GEMM1: H[64x256] = relu(Xs @ W1^T + b1), wave w handles rows w*16..+16
    // A-frag layout (16x16x32): A[m=lane&15][k=quad*8+j]
    short8 a0 = *(const short8*)&sA[(wave * 16 + l16) * LDA + quad * 8];
    short8 a1 = *(const short8*)&sA[(wave * 16 + l16) * LDA + 32 + quad * 8];
#pragma unroll
    for (int n = 0; n < 16; ++n) {
        floatx4 acc = {0.f, 0.f, 0.f, 0.f};
        // B[k][ncol] = W1[ncol][k]
        short8 b0 = *(const short8*)&sW1[(n * 16 + l16) * LDW1 + quad * 8];
        short8 bb = *(const short8*)&sW1[(n * 16 + l16) * LDW1 + 32 + quad * 8];
        acc = __builtin_amdgcn_mfma_f32_16x16x32_bf16(a0, b0, acc, 0, 0, 0);
        acc = __builtin_amdgcn_mfma_f32_16x16x32_bf16(a1, bb, acc, 0, 0, 0);
        float bias = b1[n * 16 + l16];
#pragma unroll
        for (int reg = 0; reg < 4; ++reg) {
            // C/D: col = lane&15, row = quad*4 + reg
            float h = acc[reg] + bias;
            h = h > 0.f ? h : 0.f;
            sH[(wave * 16 + quad * 4 + reg) * LDH + n * 16 + l16] = f2bf(h);
        }
    }
    __syncthreads();  // safety: sH RAW (same-wave rows, but keep it simple this round)

    // ---- GEMM2: out[64x64] = (H @ W2^T + b2) * e^s
    short8 ha[8];
#pragma unroll
    for (int t = 0; t < 8; ++t)
        ha[t] = *(const short8*)&sH[(wave * 16 + l16) * LDH + t * 32 + quad * 8];
    float mysc[4];
#pragma unroll
    for (int reg = 0; reg < 4; ++reg)
        mysc[reg] = sScale[wave * 16 + quad * 4 + reg];
#pragma unroll
    for (int n = 0; n < 4; ++n) {
        floatx4 acc = {0.f, 0.f, 0.f, 0.f};
#pragma unroll
        for (int t = 0; t < 8; ++t) {
            short8 wb = *(const short8*)&sW2[(n * 16 + l16) * LDW2 + t * 32 + quad * 8];
            acc = __builtin_amdgcn_mfma_f32_16x16x32_bf16(ha[t], wb, acc, 0, 0, 0);
        }
        float bias = b2[n * 16 + l16];
#pragma unroll
        for (int reg = 0; reg < 4; ++reg) {
            float o = (acc[reg] + bias) * mysc[reg];
            out[(m0 + wave * 16 + quad * 4 + reg) * 64 + n * 16 + l16] = o;
        }
    }
}

extern "C" void kernel_launch(void* const* d_in, const int* in_sizes, int n_in,
                              void* d_out, int out_size, void* d_ws, size_t ws_size,
                              hipStream_t stream) {
    const float* x  = (const float*)d_in[0];
    const float* r  = (const float*)d_in[1];
    const float* W1 = (const float*)d_in[2];
    const float* b1 = (const float*)d_in[3];
    const float* W2 = (const float*)d_in[4];
    const float* b2 = (const float*)d_in[5];
    float* out = (float*)d_out;
    int B = in_sizes[0] / 64;  // 262144

    char* ws = (char*)d_ws;
    unsigned short* w1b = (unsigned short*)ws;                 // 32768 B
    unsigned short* w2b = (unsigned short*)(ws + 32768);       // 32768 B
    float* scl = (float*)(ws + 65536);                         // B*4
    unsigned short* xs = (unsigned short*)(ws + 65536 + (size_t)B * 4);  // B*128

    convert_w_k<<<64, 256, 0, stream>>>(W1, W2, w1b, w2b);
    newton_k<<<B / 64, 256, 0, stream>>>(x, r, xs, scl);
    mlp_k<<<B / 64, 256, 0, stream>>>(xs, scl, w1b, w2b, b1, b2, out);
}

// Round 3
// 168.501 us; speedup vs baseline: 1.5593x; 1.5593x over previous
//
#include <hip/hip_runtime.h>

typedef __attribute__((ext_vector_type(8))) short short8;
typedef __attribute__((ext_vector_type(4))) float floatx4;

static __device__ __forceinline__ unsigned short f2bf(float f) {
    unsigned u = __float_as_uint(f);
    u += 0x7FFFu + ((u >> 16) & 1u);
    return (unsigned short)(u >> 16);
}

// ---------------- kernel 0: convert weights fp32 -> bf16 into ws ----------------
__global__ __launch_bounds__(256) void convert_w_k(const float* __restrict__ W1,
                                                   const float* __restrict__ W2,
                                                   unsigned short* __restrict__ w1b,
                                                   unsigned short* __restrict__ w2b) {
    int i = blockIdx.x * 256 + threadIdx.x;  // 16384 threads, exact
    w1b[i] = f2bf(W1[i]);
    w2b[i] = f2bf(W2[i]);
}

// ---------------- kernel 1: Newton solve for s, emit xs(bf16) and e^s ----------------
// 4 threads per sample, 16 coords each; quad-level shuffle reduction.
// FIXED 11 iterations (no tol break): analytic init is provably left-of-root
// (weighted Jensen => F(s0) >= 0, F convex decreasing) so Newton is monotone;
// typical convergence 4-5 iters, adversarial ~7. Post-convergence steps are
// ~1e-7 jitter, harmless. NOTE: the -1 of F(s)=sum-1 must be applied ONCE,
// after the quad reduction (R2 bug: per-lane -1 => sum-4).
__global__ __launch_bounds__(256) void newton_k(const float* __restrict__ x,
                                                const float* __restrict__ r,
                                                unsigned short* __restrict__ xs,
                                                float* __restrict__ scl) {
    int tid = blockIdx.x * 256 + threadIdx.x;
    int sample = tid >> 2;
    int part = tid & 3;

    const float4* x4 = (const float4*)(x + (size_t)sample * 64 + part * 16);
    const float4* r4 = (const float4*)(r + part * 16);
    float xv[16], rr[16], x2[16], rx2[16];
#pragma unroll
    for (int j = 0; j < 4; ++j) {
        float4 a = x4[j];
        float4 b = r4[j];
        xv[4 * j + 0] = a.x; xv[4 * j + 1] = a.y; xv[4 * j + 2] = a.z; xv[4 * j + 3] = a.w;
        rr[4 * j + 0] = b.x; rr[4 * j + 1] = b.y; rr[4 * j + 2] = b.z; rr[4 * j + 3] = b.w;
    }

    float sum0 = 0.f, sumr = 0.f;
    int nz = 0;
#pragma unroll
    for (int j = 0; j < 16; ++j) {
        x2[j] = xv[j] * xv[j];
        rx2[j] = rr[j] * x2[j];
        sum0 += x2[j];
        sumr += rx2[j];
        nz |= (fabsf(xv[j]) > 1e-12f) ? 1 : 0;
    }
    sum0 += __shfl_xor(sum0, 1); sum0 += __shfl_xor(sum0, 2);
    sumr += __shfl_xor(sumr, 1); sumr += __shfl_xor(sumr, 2);
    nz   |= __shfl_xor(nz, 1);   nz   |= __shfl_xor(nz, 2);

    float s = 0.f;
    if (nz) {
        s = __logf(sum0) * sum0 / (2.f * sumr);
#pragma unroll 1
        for (int it = 0; it < 11; ++it) {
            float m2s = -2.f * s;
            float v = 0.f, dv = 0.f;
#pragma unroll
            for (int j = 0; j < 16; ++j) {
                float e = __expf(m2s * rr[j]);
                v = fmaf(e, x2[j], v);
                dv = fmaf(e, rx2[j], dv);
            }
            v += __shfl_xor(v, 1);   v += __shfl_xor(v, 2);
            dv += __shfl_xor(dv, 1); dv += __shfl_xor(dv, 2);
            float val = v - 1.f;  // applied ONCE, post-reduction
            // F' = -2*dv < 0 whenever nz: no zero guard needed
            s += val / (2.f * dv);
        }
    }

    // xs = x * exp(-r*s)  (bf16), scale = exp(NU*s), NU=1
    unsigned up[8];
#pragma unroll
    for (int j = 0; j < 8; ++j) {
        float a = xv[2 * j] * __expf(-s * rr[2 * j]);
        float b = xv[2 * j + 1] * __expf(-s * rr[2 * j + 1]);
        up[j] = (unsigned)f2bf(a) | ((unsigned)f2bf(b) << 16);
    }
    uint4* dst = (uint4*)(xs + (size_t)sample * 64 + part * 16);
    dst[0] = make_uint4(up[0], up[1], up[2], up[3]);
    dst[1] = make_uint4(up[4], up[5], up[6], up[7]);
    if (part == 0) scl[sample] = __expf(s);
}

// ---------------- kernel 2: fused MLP via bf16 MFMA ----------------
// block = 256 threads (4 waves), grid-stride over 64-sample tiles.
// LDS: W1 32KB + W2 32KB + H-chunk 8KB = 72KB -> 2 blocks/CU.
// XOR swizzle (elem-chunk E>>3 of row R at position (E>>3)^(R&7)) -> <=2-way
// bank aliasing, free on CDNA4. A-frags + scales straight from global
// (contiguous 16B per lane) -> no sA stage; the H strip is wave-private
// (wave w only touches rows w*16..+15; same-wave LDS is in-order) ->
// ZERO __syncthreads in the tile loop.
__global__ __launch_bounds__(256, 2) void mlp_k(const unsigned short* __restrict__ xs,
                                                const float* __restrict__ scl,
                                                const unsigned short* __restrict__ w1b,
                                                const unsigned short* __restrict__ w2b,
                                                const float* __restrict__ b1,
                                                const float* __restrict__ b2,
                                                float* __restrict__ out,
                                                int tiles_per_block) {
    __shared__ unsigned short sW1[256 * 64];  // 32 KB, row-major [h][k], swizzled
    __shared__ unsigned short sW2[64 * 256];  // 32 KB, row-major [o][h], swizzled
    __shared__ unsigned short sH[64 * 64];    //  8 KB, H-chunk strip, swizzled

    int tid = threadIdx.x;

    // stage W1 [256x64] bf16 (2048 uint4), swizzled
    const uint4* w1u = (const uint4*)w1b;
#pragma unroll
    for (int c = 0; c < 8; ++c) {
        int g = tid + c * 256;
        int row = g >> 3, ch = g & 7;
        *(uint4*)&sW1[row * 64 + (ch ^ (row & 7)) * 8] = w1u[g];
    }
    // stage W2 [64x256] bf16 (2048 uint4), swizzled
    const uint4* w2u = (const uint4*)w2b;
#pragma unroll
    for (int c = 0; c < 8; ++c) {
        int g = tid + c * 256;
        int row = g >> 5, ch = g & 31;
        *(uint4*)&sW2[row * 256 + (ch ^ (row & 7)) * 8] = w2u[g];
    }
    __syncthreads();

    int wave = tid >> 6, lane = tid & 63;
    int q = lane >> 4, l16 = lane & 15;
    int sx = l16 & 7;  // swizzle key for rows indexed by l16

    float bias1[16];
#pragma unroll
    for (int n = 0; n < 16; ++n) bias1[n] = b1[n * 16 + l16];
    float bias2[4];
#pragma unroll
    for (int n = 0; n < 4; ++n) bias2[n] = b2[n * 16 + l16];

    for (int tt = 0; tt < tiles_per_block; ++tt) {
        size_t m0 = ((size_t)blockIdx.x * tiles_per_block + tt) * 64;
        int myrow = wave * 16 + l16;

        // A-frags (16x16x32: A[m=l16][k=q*8+j]) straight from global: 16B each
        const short8* xrow = (const short8*)(xs + (m0 + myrow) * 64);
        short8 a0 = xrow[q];
        short8 a1 = xrow[q + 4];
        float sc[4];
#pragma unroll
        for (int reg = 0; reg < 4; ++reg) sc[reg] = scl[m0 + wave * 16 + q * 4 + reg];

        floatx4 oacc[4];
#pragma unroll
        for (int n = 0; n < 4; ++n) oacc[n] = (floatx4){0.f, 0.f, 0.f, 0.f};

#pragma unroll
        for (int hc = 0; hc < 4; ++hc) {
            // ---- GEMM1: H[:, hc*64 .. +63] = relu(Xs @ W1^T + b1), 4 n-subtiles
#pragma unroll
            for (int n = 0; n < 4; ++n) {
                int hcol = hc * 4 + n;            // 16-col subtile index (0..15)
                int row = hcol * 16 + l16;        // W1 row = h index
                short8 wb0 = *(const short8*)&sW1[row * 64 + (q ^ sx) * 8];
                short8 wb1 = *(const short8*)&sW1[row * 64 + ((q + 4) ^ sx) * 8];
                floatx4 acc = {0.f, 0.f, 0.f, 0.f};
                acc = __builtin_amdgcn_mfma_f32_16x16x32_bf16(a0, wb0, acc, 0, 0, 0);
                acc = __builtin_amdgcn_mfma_f32_16x16x32_bf16(a1, wb1, acc, 0, 0, 0);
                float bias = bias1[hcol];
#pragma unroll
                for (int reg = 0; reg < 4; ++reg) {
                    // C/D: col = l16, row = q*4+reg
                    float h = acc[reg] + bias;
                    h = h > 0.f ? h : 0.f;
                    int rr = wave * 16 + q * 4 + reg;
                    int E = n * 16 + l16;  // h-local col within the 64-chunk
                    sH[rr * 64 + (((E >> 3) ^ (rr & 7)) * 8) + (E & 7)] = f2bf(h);
                }
            }
            // ---- GEMM2 partial: oacc += H_chunk @ W2_chunk^T
            short8 ha0 = *(const short8*)&sH[myrow * 64 + (q ^ sx) * 8];
            short8 ha1 = *(const short8*)&sH[myrow * 64 + ((q + 4) ^ sx) * 8];
#pragma unroll
            for (int n = 0; n < 4; ++n) {
                int row = n * 16 + l16;  // W2 row = o index
                short8 wb0 = *(const short8*)&sW2[row * 256 + (hc * 8 + (q ^ sx)) * 8];
                short8 wb1 = *(const short8*)&sW2[row * 256 + (hc * 8 + ((q + 4) ^ sx)) * 8];
                oacc[n] = __builtin_amdgcn_mfma_f32_16x16x32_bf16(ha0, wb0, oacc[n], 0, 0, 0);
                oacc[n] = __builtin_amdgcn_mfma_f32_16x16x32_bf16(ha1, wb1, oacc[n], 0, 0, 0);
            }
        }
        // ---- epilogue: out = (H @ W2^T + b2) * e^s
#pragma unroll
        for (int n = 0; n < 4; ++n) {
#pragma unroll
            for (int reg = 0; reg < 4; ++reg) {
                float o = (oacc[n][reg] + bias2[n]) * sc[reg];
                out[(m0 + wave * 16 + q * 4 + reg) * 64 + n * 16 + l16] = o;
            }
        }
    }
}

extern "C" void kernel_launch(void* const* d_in, const int* in_sizes, int n_in,
                              void* d_out, int out_size, void* d_ws, size_t ws_size,
                              hipStream_t stream) {
    const float* x  = (const float*)d_in[0];
    const float* r  = (const float*)d_in[1];
    const float* W1 = (const float*)d_in[2];
    const float* b1 = (const float*)d_in[3];
    const float* W2 = (const float*)d_in[4];
    const float* b2 = (const float*)d_in[5];
    float* out = (float*)d_out;
    int B = in_sizes[0] / 64;  // 262144

    char* ws = (char*)d_ws;
    unsigned short* w1b = (unsigned short*)ws;                 // 32768 B
    unsigned short* w2b = (unsigned short*)(ws + 32768);       // 32768 B
    float* scl = (float*)(ws + 65536);                         // B*4
    unsigned short* xs = (unsigned short*)(ws + 65536 + (size_t)B * 4);  // B*128

    convert_w_k<<<64, 256, 0, stream>>>(W1, W2, w1b, w2b);
    newton_k<<<B / 64, 256, 0, stream>>>(x, r, xs, scl);

    int tiles = B / 64;            // 4096
    int blocks = 512;              // 2 per CU
    int tpb = tiles / blocks;      // 8
    mlp_k<<<blocks, 256, 0, stream>>>(xs, scl, w1b, w2b, b1, b2, out, tpb);
}